// Round 4
// baseline (2498.354 us; speedup 1.0000x reference)
//
#include <hip/hip_runtime.h>
#include <math.h>

#define NN 9
#define RR 128
#define FF 512
#define LL 2
#define GPB 4   // graphs per block == waves per block (one 64-lane wave per graph)

__device__ __forceinline__ float4 ld4(const float* p) { return *reinterpret_cast<const float4*>(p); }
__device__ __forceinline__ float2 ld2(const float* p) { return *reinterpret_cast<const float2*>(p); }
__device__ __forceinline__ void st2(float* p, const float2 v) { *reinterpret_cast<float2*>(p) = v; }
__device__ __forceinline__ void fma2(float2& d, const float a, const float2 w) {
    d.x = fmaf(a, w.x, d.x);
    d.y = fmaf(a, w.y, d.y);
}
__device__ __forceinline__ void relu2(float2& v) {
    v.x = fmaxf(v.x, 0.f); v.y = fmaxf(v.y, 0.f);
}

// Session law (baseline/R1/R2/R3): resident waves/SIMD ~= floor(256/VGPR), not 512/VGPR.
// VGPR 124-128 -> 2/SIMD (22%); VGPR 56-64 -> ~16 waves/CU (45%). So the float4 tile
// (VGPR 128) is occupancy-capped. This version shrinks the per-lane tile to float2
// (no k-split, lane owns 2 cols, full k=128) -> est. ~60-75 VGPR demand. min-waves=3
// caps at ~85 under the law: safely above demand (no spill), guarantees 3 waves/SIMD.
__global__ __launch_bounds__(256, 3)
void backbone_kernel(const float* __restrict__ graph,
                     const int*   __restrict__ op_idx,
                     const float* __restrict__ op_table,
                     const float* __restrict__ dev_embed,
                     const float* __restrict__ gcn_W,
                     const float* __restrict__ gcn_b,
                     const float* __restrict__ ln_g,
                     const float* __restrict__ ln_b,
                     const float* __restrict__ ffn_W1,
                     const float* __restrict__ ffn_b1,
                     const float* __restrict__ ffn_W2,
                     const float* __restrict__ ffn_b2,
                     const float* __restrict__ fc_w,
                     const float* __restrict__ fc_b,
                     float* __restrict__ out)
{
    // One wave per graph slot; no __syncthreads anywhere (wave-private LDS slices,
    // in-wave DS ordering via compiler-inserted lgkmcnt waits).
    __shared__ float sX[GPB][NN][RR];   // x  / h_ln
    __shared__ float sT[GPB][NN][RR];   // agg / ffn hidden chunk
    __shared__ float sNA[GPB][81];
    __shared__ float sD[GPB][NN];

    const int tid  = threadIdx.x;        // 0..255
    const int lane = tid & 63;           // lane within wave
    const int ms   = tid >> 6;           // wave index == graph slot (0..3)
    const int c0   = lane * 2;           // this lane's 2 columns (0..126)
    const int g    = blockIdx.x * GPB + ms;

    // ---- per-wave staging: x = op_table[op_idx] + dev_embed ----
    {
        const float2 dv = ld2(&dev_embed[c0]);
        #pragma unroll
        for (int j = 0; j < NN; ++j) {
            const int idx = op_idx[g * NN + j];          // wave-uniform -> s_load
            float2 v = ld2(&op_table[idx * RR + c0]);
            v.x += dv.x; v.y += dv.y;
            st2(&sX[ms][j][c0], v);
        }
    }

    // ---- per-wave adjacency normalization (a_hat, rsqrt degrees, norm) ----
    {
        const float* gp = graph + (size_t)g * 81;
        {   // raw a_hat -> sNA (elements 0..63)
            const int i = lane / NN, j = lane - i * NN;
            sNA[ms][lane] = gp[lane] + (i == j ? 1.0f : 0.0f);
        }
        if (lane < 17) {  // elements 64..80
            const int e = lane + 64;
            const int i = e / NN, j = e - i * NN;
            sNA[ms][e] = gp[e] + (i == j ? 1.0f : 0.0f);
        }
        if (lane < NN) {  // row sums -> rsqrt
            float s = 0.f;
            #pragma unroll
            for (int j = 0; j < NN; ++j) s += sNA[ms][lane * NN + j];
            sD[ms][lane] = rsqrtf(s);
        }
        {   // normalize in place
            const int i = lane / NN, j = lane - i * NN;
            sNA[ms][lane] *= sD[ms][i] * sD[ms][j];
        }
        if (lane < 17) {
            const int e = lane + 64;
            const int i = e / NN, j = e - i * NN;
            sNA[ms][e] *= sD[ms][i] * sD[ms][j];
        }
    }

    float2 acc[NN];   // FFN output / final features (compile-time indexed ONLY)

    for (int l = 0; l < LL; ++l) {
        const float* gw = gcn_W  + l * RR * RR;
        const float* gb = gcn_b  + l * RR;
        const float* lg = ln_g   + l * RR;
        const float* lb = ln_b   + l * RR;
        const float* w1 = ffn_W1 + l * RR * FF;
        const float* b1 = ffn_b1 + l * FF;
        const float* w2 = ffn_W2 + l * FF * RR;
        const float* b2 = ffn_b2 + l * RR;

        // ---- agg = norm_adj @ x -> sT (each lane: all 9 rows, its 2 cols) ----
        {
            float2 xv[NN];
            #pragma unroll
            for (int j = 0; j < NN; ++j) xv[j] = ld2(&sX[ms][j][c0]);
            #pragma unroll
            for (int i = 0; i < NN; ++i) {
                float2 a = make_float2(0.f, 0.f);
                #pragma unroll
                for (int j = 0; j < NN; ++j) fma2(a, sNA[ms][i * NN + j], xv[j]);
                st2(&sT[ms][i][c0], a);
            }
        }

        // ---- h = agg @ gcn_W + gcn_b (full k=128 per lane) ----
        float2 h[NN];
        {
            const float2 gbv = ld2(&gb[c0]);
            #pragma unroll
            for (int i = 0; i < NN; ++i) h[i] = gbv;
            for (int kk = 0; kk < RR; kk += 4) {
                const float* wp = gw + (size_t)kk * RR + c0;
                const float2 wv0 = ld2(wp);
                const float2 wv1 = ld2(wp + RR);
                const float2 wv2 = ld2(wp + 2 * RR);
                const float2 wv3 = ld2(wp + 3 * RR);
                #pragma unroll
                for (int i = 0; i < NN; ++i) {
                    const float4 a = ld4(&sT[ms][i][kk]);   // wave-uniform broadcast
                    fma2(h[i], a.x, wv0); fma2(h[i], a.y, wv1);
                    fma2(h[i], a.z, wv2); fma2(h[i], a.w, wv3);
                }
            }
        }

        // ---- relu + layernorm (reduce across all 64 lanes, 2 cols each) ----
        {
            const float2 lgv = ld2(&lg[c0]);
            const float2 lbv = ld2(&lb[c0]);
            #pragma unroll
            for (int i = 0; i < NN; ++i) {
                float2 v = h[i];
                relu2(v);
                float s = v.x + v.y;
                float q = v.x * v.x + v.y * v.y;
                #pragma unroll
                for (int m = 1; m <= 32; m <<= 1) {
                    s += __shfl_xor(s, m);
                    q += __shfl_xor(q, m);
                }
                const float mu  = s * (1.f / RR);
                const float var = q * (1.f / RR) - mu * mu;
                const float rs  = rsqrtf(var + 1e-5f);
                v.x = (v.x - mu) * rs * lgv.x + lbv.x;
                v.y = (v.y - mu) * rs * lgv.y + lbv.y;
                h[i] = v;
            }
        }

        // h_ln -> sX, residual init acc = h_ln + ffn_b2
        {
            const float2 b2v = ld2(&b2[c0]);
            #pragma unroll
            for (int i = 0; i < NN; ++i) {
                st2(&sX[ms][i][c0], h[i]);
                acc[i].x = h[i].x + b2v.x;
                acc[i].y = h[i].y + b2v.y;
            }
        }

        // ---- FFN: 4 passes over F=512 in 128-wide chunks ----
        for (int p = 0; p < 4; ++p) {
            const int f0 = p * RR + c0;
            float2 t[NN];
            {
                const float2 b1v = ld2(&b1[f0]);
                #pragma unroll
                for (int i = 0; i < NN; ++i) t[i] = b1v;
            }
            for (int kk = 0; kk < RR; kk += 4) {
                const float* wp = w1 + (size_t)kk * FF + f0;
                const float2 wv0 = ld2(wp);
                const float2 wv1 = ld2(wp + FF);
                const float2 wv2 = ld2(wp + 2 * FF);
                const float2 wv3 = ld2(wp + 3 * FF);
                #pragma unroll
                for (int i = 0; i < NN; ++i) {
                    const float4 a = ld4(&sX[ms][i][kk]);
                    fma2(t[i], a.x, wv0); fma2(t[i], a.y, wv1);
                    fma2(t[i], a.z, wv2); fma2(t[i], a.w, wv3);
                }
            }
            #pragma unroll
            for (int i = 0; i < NN; ++i) {
                relu2(t[i]);
                st2(&sT[ms][i][c0], t[i]);
            }
            for (int kk = 0; kk < RR; kk += 4) {
                const float* wp = w2 + (size_t)(p * RR + kk) * RR + c0;
                const float2 wv0 = ld2(wp);
                const float2 wv1 = ld2(wp + RR);
                const float2 wv2 = ld2(wp + 2 * RR);
                const float2 wv3 = ld2(wp + 3 * RR);
                #pragma unroll
                for (int i = 0; i < NN; ++i) {
                    const float4 a = ld4(&sT[ms][i][kk]);
                    fma2(acc[i], a.x, wv0); fma2(acc[i], a.y, wv1);
                    fma2(acc[i], a.z, wv2); fma2(acc[i], a.w, wv3);
                }
            }
        }

        // new x for next layer
        if (l + 1 < LL) {
            #pragma unroll
            for (int i = 0; i < NN; ++i) st2(&sX[ms][i][c0], acc[i]);
        }
    }

    // ---- readout: mean over nodes, dot fc_w, sigmoid ----
    {
        const float2 fw = ld2(&fc_w[c0]);
        float2 pv = make_float2(0.f, 0.f);
        #pragma unroll
        for (int i = 0; i < NN; ++i) {
            pv.x += acc[i].x; pv.y += acc[i].y;
        }
        float part = (pv.x * fw.x + pv.y * fw.y) * (1.f / 9.f);
        #pragma unroll
        for (int m = 1; m <= 32; m <<= 1) part += __shfl_xor(part, m);
        if (lane == 0) {
            const float yv = part + fc_b[0];
            out[g] = 1.f / (1.f + expf(-yv));
        }
    }
}

extern "C" void kernel_launch(void* const* d_in, const int* in_sizes, int n_in,
                              void* d_out, int out_size, void* d_ws, size_t ws_size,
                              hipStream_t stream) {
    const float* graph     = (const float*)d_in[0];
    const int*   op_idx    = (const int*)  d_in[1];
    const float* op_table  = (const float*)d_in[2];
    const float* dev_embed = (const float*)d_in[3];
    const float* gcn_W     = (const float*)d_in[4];
    const float* gcn_b     = (const float*)d_in[5];
    const float* ln_g      = (const float*)d_in[6];
    const float* ln_b      = (const float*)d_in[7];
    const float* ffn_W1    = (const float*)d_in[8];
    const float* ffn_b1    = (const float*)d_in[9];
    const float* ffn_W2    = (const float*)d_in[10];
    const float* ffn_b2    = (const float*)d_in[11];
    const float* fc_w      = (const float*)d_in[12];
    const float* fc_b      = (const float*)d_in[13];
    float* out = (float*)d_out;

    const int nB = in_sizes[0] / 81;          // 32768
    dim3 grid(nB / GPB), block(256);
    backbone_kernel<<<grid, block, 0, stream>>>(
        graph, op_idx, op_table, dev_embed, gcn_W, gcn_b, ln_g, ln_b,
        ffn_W1, ffn_b1, ffn_W2, ffn_b2, fc_w, fc_b, out);
}

// Round 6
// 820.880 us; speedup vs baseline: 3.0435x; 3.0435x over previous
//
#include <hip/hip_runtime.h>
#include <math.h>

#define NN 9
#define RR 128
#define FF 512
#define LL 2
#define GPB 4   // graphs per block == waves per block (one 64-lane wave per graph)

typedef __attribute__((ext_vector_type(8))) short bf16x8;  // 8 bf16 = 4 VGPRs
typedef __attribute__((ext_vector_type(4))) float f32x4;

__device__ __forceinline__ float4 ld4(const float* p) { return *reinterpret_cast<const float4*>(p); }
__device__ __forceinline__ float2 ld2(const float* p) { return *reinterpret_cast<const float2*>(p); }
__device__ __forceinline__ void st4(float* p, const float4 v) { *reinterpret_cast<float4*>(p) = v; }

__device__ __forceinline__ ushort f2bf(float f) {   // fp32 -> bf16 RNE
    unsigned u = __float_as_uint(f);
    return (ushort)((u + 0x7fffu + ((u >> 16) & 1u)) >> 16);
}
__device__ __forceinline__ float bf2f(ushort h) { return __uint_as_float(((unsigned)h) << 16); }

// LDS activation buffers: [10 rows][128 bf16], row 9 = zeros (M-pad target).
// Row stride 256B => 16-way bank conflict on the A-frag ds_read_b128 without a
// swizzle (G4). XOR slot swizzle in ushort units: c ^ ((row&7)<<3).
#define SWZ(row, c) ((row) * 128 + ((c) ^ (((row) & 7) << 3)))

// ---------------- pre-kernel: fp32 weights -> frag-packed bf16 in d_ws ----------------
// Frag chunk = 64 lanes x 16B (8 bf16, consecutive k). Chunk linear index:
//   gcn : (l*4 + ks)*8 + nt                       (64 chunks,  64 KB)
//   W1  : 64  + ((l*4 + p)*4 + ks)*8 + nt         (256 chunks, 256 KB)
//   W2  : 320 + ((l*4 + p)*4 + ks)*8 + nt         (256 chunks, 256 KB)
// B-frag element j of lane: k = kbase + j, n = nt*16 + (lane&15).
__global__ __launch_bounds__(256)
void pack_weights(const float* __restrict__ gcn_W,
                  const float* __restrict__ ffn_W1,
                  const float* __restrict__ ffn_W2,
                  ushort* __restrict__ wsw)
{
    const int t    = blockIdx.x * 256 + threadIdx.x;  // 0..36863
    const int lane = t & 63;
    const int slot = t >> 6;                          // 0..575
    const int grp  = lane >> 4, cl = lane & 15;

    const float* src; int ldn, kbase, n;
    if (slot < 64) {
        const int l = slot >> 5, ks = (slot >> 3) & 3, nt = slot & 7;
        src = gcn_W + l * RR * RR; ldn = RR;
        kbase = ks * 32 + grp * 8;
        n = nt * 16 + cl;
    } else if (slot < 320) {
        const int s = slot - 64;
        const int l = s >> 7, p = (s >> 5) & 3, ks = (s >> 3) & 3, nt = s & 7;
        src = ffn_W1 + l * RR * FF; ldn = FF;
        kbase = ks * 32 + grp * 8;
        n = p * 128 + nt * 16 + cl;
    } else {
        const int s = slot - 320;
        const int l = s >> 7, p = (s >> 5) & 3, ks = (s >> 3) & 3, nt = s & 7;
        src = ffn_W2 + l * FF * RR; ldn = RR;
        kbase = p * 128 + ks * 32 + grp * 8;
        n = nt * 16 + cl;
    }
    ushort v[8];
    #pragma unroll
    for (int j = 0; j < 8; ++j) v[j] = f2bf(src[(size_t)(kbase + j) * ldn + n]);
    uint4 o;
    o.x = v[0] | ((unsigned)v[1] << 16);
    o.y = v[2] | ((unsigned)v[3] << 16);
    o.z = v[4] | ((unsigned)v[5] << 16);
    o.w = v[6] | ((unsigned)v[7] << 16);
    *reinterpret_cast<uint4*>(wsw + ((size_t)slot * 64 + lane) * 8) = o;
}

// ---------------- main kernel: one wave per graph, MFMA 16x16x32 bf16 ----------------
__global__ __launch_bounds__(256, 2)
void backbone_mfma(const float* __restrict__ graph,
                   const int*   __restrict__ op_idx,
                   const float* __restrict__ op_table,
                   const float* __restrict__ dev_embed,
                   const float* __restrict__ gcn_b,
                   const float* __restrict__ ln_g,
                   const float* __restrict__ ln_b,
                   const float* __restrict__ ffn_b1,
                   const float* __restrict__ ffn_b2,
                   const float* __restrict__ fc_w,
                   const float* __restrict__ fc_b,
                   const ushort* __restrict__ wsw,
                   float* __restrict__ out)
{
    // wave-private LDS slices; zero __syncthreads in the whole kernel
    __shared__ alignas(16) ushort sA[GPB][1280];  // x / h_ln (bf16, swizzled)
    __shared__ alignas(16) ushort sG[GPB][1280];  // agg (bf16, swizzled)
    __shared__ alignas(16) ushort sH[GPB][1280];  // ffn hidden chunk (bf16, swizzled)
    __shared__ float sNA[GPB][81];
    __shared__ float sD[GPB][NN];

    const int tid  = threadIdx.x;
    const int lane = tid & 63;
    const int ms   = tid >> 6;
    const int grp  = lane >> 4;       // row-group for MFMA frags
    const int cl   = lane & 15;       // col within tile / A-row
    const int arow = (cl < NN) ? cl : NN;   // A-frag row, pad rows -> zero row 9
    const int c0   = lane * 2;        // this lane's 2 cols for staging/agg
    const int g    = blockIdx.x * GPB + ms;

    const bf16x8* wb = reinterpret_cast<const bf16x8*>(wsw);

    // zero row 9 of all three activation buffers (M-pad rows read zeros)
    *reinterpret_cast<unsigned*>(&sA[ms][SWZ(9, c0)]) = 0u;
    *reinterpret_cast<unsigned*>(&sG[ms][SWZ(9, c0)]) = 0u;
    *reinterpret_cast<unsigned*>(&sH[ms][SWZ(9, c0)]) = 0u;

    // ---- stage x = op_table[op_idx] + dev_embed  (bf16, swizzled rows) ----
    {
        const float2 dv = ld2(&dev_embed[c0]);
        #pragma unroll
        for (int j = 0; j < NN; ++j) {
            const int idx = op_idx[g * NN + j];            // wave-uniform
            float2 v = ld2(&op_table[idx * RR + c0]);
            unsigned pk = f2bf(v.x + dv.x) | ((unsigned)f2bf(v.y + dv.y) << 16);
            *reinterpret_cast<unsigned*>(&sA[ms][SWZ(j, c0)]) = pk;
        }
    }

    // ---- adjacency normalization (fp32, as before) ----
    {
        const float* gp = graph + (size_t)g * 81;
        {
            const int i = lane / NN, j = lane - i * NN;
            sNA[ms][lane] = gp[lane] + (i == j ? 1.0f : 0.0f);
        }
        if (lane < 17) {
            const int e = lane + 64;
            const int i = e / NN, j = e - i * NN;
            sNA[ms][e] = gp[e] + (i == j ? 1.0f : 0.0f);
        }
        if (lane < NN) {
            float s = 0.f;
            #pragma unroll
            for (int j = 0; j < NN; ++j) s += sNA[ms][lane * NN + j];
            sD[ms][lane] = rsqrtf(s);
        }
        {
            const int i = lane / NN, j = lane - i * NN;
            sNA[ms][lane] *= sD[ms][i] * sD[ms][j];
        }
        if (lane < 17) {
            const int e = lane + 64;
            const int i = e / NN, j = e - i * NN;
            sNA[ms][e] *= sD[ms][i] * sD[ms][j];
        }
    }

    f32x4 acc[8];   // MFMA C-layout accumulator; function scope (readout uses it)

    for (int l = 0; l < LL; ++l) {
        // ---- agg = norm_adj @ x  (fp32 VALU on bf16 x; tiny) -> sG bf16 ----
        {
            float xr[NN * 2];
            #pragma unroll
            for (int j = 0; j < NN; ++j) {
                unsigned u = *reinterpret_cast<const unsigned*>(&sA[ms][SWZ(j, c0)]);
                xr[2 * j]     = bf2f((ushort)(u & 0xffffu));
                xr[2 * j + 1] = bf2f((ushort)(u >> 16));
            }
            #pragma unroll
            for (int i = 0; i < NN; ++i) {
                float a0 = 0.f, a1 = 0.f;
                #pragma unroll
                for (int j = 0; j < NN; ++j) {
                    const float w = sNA[ms][i * NN + j];
                    a0 = fmaf(w, xr[2 * j], a0);
                    a1 = fmaf(w, xr[2 * j + 1], a1);
                }
                unsigned pk = f2bf(a0) | ((unsigned)f2bf(a1) << 16);
                *reinterpret_cast<unsigned*>(&sG[ms][SWZ(i, c0)]) = pk;
            }
        }

        // ---- h = agg @ gcn_W via MFMA ----
        #pragma unroll
        for (int nt = 0; nt < 8; ++nt) acc[nt] = (f32x4){0.f, 0.f, 0.f, 0.f};
        #pragma unroll
        for (int ks = 0; ks < 4; ++ks) {
            const bf16x8 af = *reinterpret_cast<const bf16x8*>(&sG[ms][SWZ(arow, ks * 32 + grp * 8)]);
            const bf16x8* bp = wb + (size_t)(((l * 4 + ks) * 8) * 64 + lane);
            #pragma unroll
            for (int nt = 0; nt < 8; ++nt)
                acc[nt] = __builtin_amdgcn_mfma_f32_16x16x32_bf16(af, bp[nt * 64], acc[nt], 0, 0, 0);
        }

        // ---- + bias, relu, layernorm (C-layout: col = nt*16+cl, rows grp*4+r) ----
        {
            float sv[4] = {0.f, 0.f, 0.f, 0.f}, qv[4] = {0.f, 0.f, 0.f, 0.f};
            #pragma unroll
            for (int nt = 0; nt < 8; ++nt) {
                const float gb = gcn_b[l * RR + nt * 16 + cl];
                #pragma unroll
                for (int r = 0; r < 4; ++r) {
                    float v = fmaxf(acc[nt][r] + gb, 0.f);
                    acc[nt][r] = v;
                    sv[r] += v; qv[r] += v * v;
                }
            }
            #pragma unroll
            for (int r = 0; r < 4; ++r) {
                #pragma unroll
                for (int m = 1; m <= 8; m <<= 1) {   // row lives in a 16-lane group
                    sv[r] += __shfl_xor(sv[r], m);
                    qv[r] += __shfl_xor(qv[r], m);
                }
            }
            float mu[4], rs[4];
            #pragma unroll
            for (int r = 0; r < 4; ++r) {
                mu[r] = sv[r] * (1.f / RR);
                const float var = qv[r] * (1.f / RR) - mu[r] * mu[r];
                rs[r] = rsqrtf(var + 1e-5f);
            }
            #pragma unroll
            for (int nt = 0; nt < 8; ++nt) {
                const float lgv = ln_g[l * RR + nt * 16 + cl];
                const float lbv = ln_b[l * RR + nt * 16 + cl];
                #pragma unroll
                for (int r = 0; r < 4; ++r)
                    acc[nt][r] = (acc[nt][r] - mu[r]) * rs[r] * lgv + lbv;
            }
        }

        // h_ln -> sA (bf16 scatter, valid rows only); then acc becomes the
        // FFN residual accumulator in place: acc += ffn_b2
        #pragma unroll
        for (int nt = 0; nt < 8; ++nt) {
            #pragma unroll
            for (int r = 0; r < 4; ++r) {
                const int row = grp * 4 + r;
                if (row < NN) sA[ms][SWZ(row, nt * 16 + cl)] = f2bf(acc[nt][r]);
            }
        }
        #pragma unroll
        for (int nt = 0; nt < 8; ++nt) {
            const float b2v = ffn_b2[l * RR + nt * 16 + cl];
            #pragma unroll
            for (int r = 0; r < 4; ++r) acc[nt][r] += b2v;
        }

        // ---- FFN: 4 passes over F=512 ----
        for (int p = 0; p < 4; ++p) {
            f32x4 t[8];
            #pragma unroll
            for (int nt = 0; nt < 8; ++nt) {
                const float b1v = ffn_b1[l * FF + p * 128 + nt * 16 + cl];
                t[nt] = (f32x4){b1v, b1v, b1v, b1v};
            }
            #pragma unroll
            for (int ks = 0; ks < 4; ++ks) {
                const bf16x8 af = *reinterpret_cast<const bf16x8*>(&sA[ms][SWZ(arow, ks * 32 + grp * 8)]);
                const bf16x8* bp = wb + (size_t)((64 + (l * 4 + p) * 32 + ks * 8) * 64 + lane);
                #pragma unroll
                for (int nt = 0; nt < 8; ++nt)
                    t[nt] = __builtin_amdgcn_mfma_f32_16x16x32_bf16(af, bp[nt * 64], t[nt], 0, 0, 0);
            }
            // relu -> hidden chunk to sH (bf16)
            #pragma unroll
            for (int nt = 0; nt < 8; ++nt) {
                #pragma unroll
                for (int r = 0; r < 4; ++r) {
                    const int row = grp * 4 + r;
                    if (row < NN) sH[ms][SWZ(row, nt * 16 + cl)] = f2bf(fmaxf(t[nt][r], 0.f));
                }
            }
            #pragma unroll
            for (int ks = 0; ks < 4; ++ks) {
                const bf16x8 af = *reinterpret_cast<const bf16x8*>(&sH[ms][SWZ(arow, ks * 32 + grp * 8)]);
                const bf16x8* bp = wb + (size_t)((320 + (l * 4 + p) * 32 + ks * 8) * 64 + lane);
                #pragma unroll
                for (int nt = 0; nt < 8; ++nt)
                    acc[nt] = __builtin_amdgcn_mfma_f32_16x16x32_bf16(af, bp[nt * 64], acc[nt], 0, 0, 0);
            }
        }

        // next-layer x
        if (l + 1 < LL) {
            #pragma unroll
            for (int nt = 0; nt < 8; ++nt) {
                #pragma unroll
                for (int r = 0; r < 4; ++r) {
                    const int row = grp * 4 + r;
                    if (row < NN) sA[ms][SWZ(row, nt * 16 + cl)] = f2bf(acc[nt][r]);
                }
            }
        }
    }

    // ---- readout: mean over 9 nodes, dot fc_w, sigmoid ----
    {
        float part = 0.f;
        #pragma unroll
        for (int nt = 0; nt < 8; ++nt) {
            float s = 0.f;
            #pragma unroll
            for (int r = 0; r < 4; ++r) {
                const int row = grp * 4 + r;
                s += (row < NN) ? acc[nt][r] : 0.f;
            }
            s += __shfl_xor(s, 16);
            s += __shfl_xor(s, 32);
            part += s * fc_w[nt * 16 + cl];
        }
        part *= (1.f / 9.f);
        #pragma unroll
        for (int m = 1; m <= 8; m <<= 1) part += __shfl_xor(part, m);
        if (lane == 0) out[g] = 1.f / (1.f + expf(-(part + fc_b[0])));
    }
}

// ---------------- fp32 fallback (round-3 kernel, used if d_ws too small) ----------------
__device__ __forceinline__ void fma4(float4& d, const float a, const float4 w) {
    d.x = fmaf(a, w.x, d.x); d.y = fmaf(a, w.y, d.y);
    d.z = fmaf(a, w.z, d.z); d.w = fmaf(a, w.w, d.w);
}
__device__ __forceinline__ void xadd32(float4& v) {
    v.x += __shfl_xor(v.x, 32); v.y += __shfl_xor(v.y, 32);
    v.z += __shfl_xor(v.z, 32); v.w += __shfl_xor(v.w, 32);
}
__device__ __forceinline__ void relu4f(float4& v) {
    v.x = fmaxf(v.x, 0.f); v.y = fmaxf(v.y, 0.f);
    v.z = fmaxf(v.z, 0.f); v.w = fmaxf(v.w, 0.f);
}

__global__ __launch_bounds__(256)
void backbone_fp32(const float* __restrict__ graph, const int* __restrict__ op_idx,
                   const float* __restrict__ op_table, const float* __restrict__ dev_embed,
                   const float* __restrict__ gcn_W, const float* __restrict__ gcn_b,
                   const float* __restrict__ ln_g, const float* __restrict__ ln_b,
                   const float* __restrict__ ffn_W1, const float* __restrict__ ffn_b1,
                   const float* __restrict__ ffn_W2, const float* __restrict__ ffn_b2,
                   const float* __restrict__ fc_w, const float* __restrict__ fc_b,
                   float* __restrict__ out)
{
    __shared__ float sX[GPB][NN][RR];
    __shared__ float sT[GPB][NN][RR];
    __shared__ float sNA[GPB][81];
    __shared__ float sD[GPB][NN];

    const int tid  = threadIdx.x;
    const int lane = tid & 63;
    const int cg   = tid & 31;
    const int half = (tid >> 5) & 1;
    const int ms   = tid >> 6;
    const int c0   = cg * 4;
    const int k0   = half * 64;
    const int g    = blockIdx.x * GPB + ms;

    {
        const float dv0 = dev_embed[lane];
        const float dv1 = dev_embed[lane + 64];
        #pragma unroll
        for (int j = 0; j < NN; ++j) {
            const int idx = op_idx[g * NN + j];
            sX[ms][j][lane]      = op_table[idx * RR + lane]      + dv0;
            sX[ms][j][lane + 64] = op_table[idx * RR + lane + 64] + dv1;
        }
    }
    {
        const float* gp = graph + (size_t)g * 81;
        { const int i = lane / NN, j = lane - i * NN;
          sNA[ms][lane] = gp[lane] + (i == j ? 1.0f : 0.0f); }
        if (lane < 17) { const int e = lane + 64; const int i = e / NN, j = e - i * NN;
          sNA[ms][e] = gp[e] + (i == j ? 1.0f : 0.0f); }
        if (lane < NN) {
            float s = 0.f;
            #pragma unroll
            for (int j = 0; j < NN; ++j) s += sNA[ms][lane * NN + j];
            sD[ms][lane] = rsqrtf(s);
        }
        { const int i = lane / NN, j = lane - i * NN; sNA[ms][lane] *= sD[ms][i] * sD[ms][j]; }
        if (lane < 17) { const int e = lane + 64; const int i = e / NN, j = e - i * NN;
          sNA[ms][e] *= sD[ms][i] * sD[ms][j]; }
    }

    float4 acc[NN];
    for (int l = 0; l < LL; ++l) {
        const float* gw = gcn_W  + l * RR * RR;
        const float* gb = gcn_b  + l * RR;
        const float* lg = ln_g   + l * RR;
        const float* lb = ln_b   + l * RR;
        const float* w1 = ffn_W1 + l * RR * FF;
        const float* b1 = ffn_b1 + l * FF;
        const float* w2 = ffn_W2 + l * FF * RR;
        const float* b2 = ffn_b2 + l * RR;
        {
            float4 xv[NN];
            #pragma unroll
            for (int j = 0; j < NN; ++j) xv[j] = ld4(&sX[ms][j][c0]);
            #pragma unroll
            for (int ii = 0; ii < 5; ++ii) {
                const int i = ii + half * 5;
                if (i < NN) {
                    float4 a = make_float4(0.f, 0.f, 0.f, 0.f);
                    #pragma unroll
                    for (int j = 0; j < NN; ++j) fma4(a, sNA[ms][i * NN + j], xv[j]);
                    st4(&sT[ms][i][c0], a);
                }
            }
        }
        float4 h[NN];
        {
            const float4 z4 = make_float4(0.f, 0.f, 0.f, 0.f);
            const float4 gbv = ld4(&gb[c0]);
            const float4 ini = half ? z4 : gbv;
            #pragma unroll
            for (int i = 0; i < NN; ++i) h[i] = ini;
            #pragma unroll 2
            for (int kk = 0; kk < 64; kk += 4) {
                const float* wp = gw + (size_t)(k0 + kk) * RR + c0;
                const float4 wv0 = ld4(wp), wv1 = ld4(wp + RR), wv2 = ld4(wp + 2 * RR), wv3 = ld4(wp + 3 * RR);
                #pragma unroll
                for (int i = 0; i < NN; ++i) {
                    const float4 a = ld4(&sT[ms][i][k0 + kk]);
                    fma4(h[i], a.x, wv0); fma4(h[i], a.y, wv1);
                    fma4(h[i], a.z, wv2); fma4(h[i], a.w, wv3);
                }
            }
            #pragma unroll
            for (int i = 0; i < NN; ++i) xadd32(h[i]);
        }
        {
            const float4 lgv = ld4(&lg[c0]);
            const float4 lbv = ld4(&lb[c0]);
            #pragma unroll
            for (int i = 0; i < NN; ++i) {
                float4 v = h[i]; relu4f(v);
                float s = v.x + v.y + v.z + v.w;
                float q = v.x*v.x + v.y*v.y + v.z*v.z + v.w*v.w;
                #pragma unroll
                for (int m = 1; m <= 16; m <<= 1) { s += __shfl_xor(s, m); q += __shfl_xor(q, m); }
                const float mu = s * (1.f / RR);
                const float var = q * (1.f / RR) - mu * mu;
                const float rs = rsqrtf(var + 1e-5f);
                v.x = (v.x - mu) * rs * lgv.x + lbv.x;
                v.y = (v.y - mu) * rs * lgv.y + lbv.y;
                v.z = (v.z - mu) * rs * lgv.z + lbv.z;
                v.w = (v.w - mu) * rs * lgv.w + lbv.w;
                h[i] = v;
            }
        }
        #pragma unroll
        for (int i = 0; i < NN; ++i) st4(&sX[ms][i][c0], h[i]);
        {
            const float4 b2v = ld4(&b2[c0]);
            #pragma unroll
            for (int i = 0; i < NN; ++i) {
                if (half) acc[i] = make_float4(0.f, 0.f, 0.f, 0.f);
                else { acc[i] = h[i];
                       acc[i].x += b2v.x; acc[i].y += b2v.y; acc[i].z += b2v.z; acc[i].w += b2v.w; }
            }
        }
        for (int p = 0; p < 4; ++p) {
            const int f0 = p * RR + c0;
            float4 t[NN];
            {
                const float4 z4 = make_float4(0.f, 0.f, 0.f, 0.f);
                const float4 b1v = ld4(&b1[f0]);
                const float4 ini = half ? z4 : b1v;
                #pragma unroll
                for (int i = 0; i < NN; ++i) t[i] = ini;
            }
            #pragma unroll 2
            for (int kk = 0; kk < 64; kk += 4) {
                const float* wp = w1 + (size_t)(k0 + kk) * FF + f0;
                const float4 wv0 = ld4(wp), wv1 = ld4(wp + FF), wv2 = ld4(wp + 2 * FF), wv3 = ld4(wp + 3 * FF);
                #pragma unroll
                for (int i = 0; i < NN; ++i) {
                    const float4 a = ld4(&sX[ms][i][k0 + kk]);
                    fma4(t[i], a.x, wv0); fma4(t[i], a.y, wv1);
                    fma4(t[i], a.z, wv2); fma4(t[i], a.w, wv3);
                }
            }
            #pragma unroll
            for (int i = 0; i < NN; ++i) { xadd32(t[i]); relu4f(t[i]); st4(&sT[ms][i][c0], t[i]); }
            #pragma unroll 2
            for (int kk = 0; kk < 64; kk += 4) {
                const float* wp = w2 + (size_t)(p * RR + k0 + kk) * RR + c0;
                const float4 wv0 = ld4(wp), wv1 = ld4(wp + RR), wv2 = ld4(wp + 2 * RR), wv3 = ld4(wp + 3 * RR);
                #pragma unroll
                for (int i = 0; i < NN; ++i) {
                    const float4 a = ld4(&sT[ms][i][k0 + kk]);
                    fma4(acc[i], a.x, wv0); fma4(acc[i], a.y, wv1);
                    fma4(acc[i], a.z, wv2); fma4(acc[i], a.w, wv3);
                }
            }
        }
        #pragma unroll
        for (int i = 0; i < NN; ++i) xadd32(acc[i]);
        if (l + 1 < LL) {
            #pragma unroll
            for (int i = 0; i < NN; ++i) st4(&sX[ms][i][c0], acc[i]);
        }
    }
    {
        const float4 fw = ld4(&fc_w[c0]);
        float4 pv = make_float4(0.f, 0.f, 0.f, 0.f);
        #pragma unroll
        for (int i = 0; i < NN; ++i) { pv.x += acc[i].x; pv.y += acc[i].y; pv.z += acc[i].z; pv.w += acc[i].w; }
        float part = (pv.x*fw.x + pv.y*fw.y + pv.z*fw.z + pv.w*fw.w) * (1.f / 9.f);
        #pragma unroll
        for (int m = 1; m <= 16; m <<= 1) part += __shfl_xor(part, m);
        if (lane == 0) out[g] = 1.f / (1.f + expf(-(part + fc_b[0])));
    }
}

extern "C" void kernel_launch(void* const* d_in, const int* in_sizes, int n_in,
                              void* d_out, int out_size, void* d_ws, size_t ws_size,
                              hipStream_t stream) {
    const float* graph     = (const float*)d_in[0];
    const int*   op_idx    = (const int*)  d_in[1];
    const float* op_table  = (const float*)d_in[2];
    const float* dev_embed = (const float*)d_in[3];
    const float* gcn_W     = (const float*)d_in[4];
    const float* gcn_b     = (const float*)d_in[5];
    const float* ln_g      = (const float*)d_in[6];
    const float* ln_b      = (const float*)d_in[7];
    const float* ffn_W1    = (const float*)d_in[8];
    const float* ffn_b1    = (const float*)d_in[9];
    const float* ffn_W2    = (const float*)d_in[10];
    const float* ffn_b2    = (const float*)d_in[11];
    const float* fc_w      = (const float*)d_in[12];
    const float* fc_b      = (const float*)d_in[13];
    float* out = (float*)d_out;

    const int nB = in_sizes[0] / 81;          // 32768
    const size_t WS_NEED = 576 * 1024;        // frag-packed bf16 weights

    if (d_ws != nullptr && ws_size >= WS_NEED) {
        pack_weights<<<dim3(144), dim3(256), 0, stream>>>(gcn_W, ffn_W1, ffn_W2, (ushort*)d_ws);
        backbone_mfma<<<dim3(nB / GPB), dim3(256), 0, stream>>>(
            graph, op_idx, op_table, dev_embed, gcn_b, ln_g, ln_b,
            ffn_b1, ffn_b2, fc_w, fc_b, (const ushort*)d_ws, out);
    } else {
        backbone_fp32<<<dim3(nB / GPB), dim3(256), 0, stream>>>(
            graph, op_idx, op_table, dev_embed, gcn_W, gcn_b, ln_g, ln_b,
            ffn_W1, ffn_b1, ffn_W2, ffn_b2, fc_w, fc_b, out);
    }
}

// Round 7
// 560.041 us; speedup vs baseline: 4.4610x; 1.4657x over previous
//
#include <hip/hip_runtime.h>
#include <math.h>

#define NN 9
#define RR 128
#define FF 512
#define LL 2
#define GPB 4   // graphs per block == waves per block (one 64-lane wave per graph)

typedef __attribute__((ext_vector_type(8))) short bf16x8;  // 8 bf16 = 4 VGPRs
typedef __attribute__((ext_vector_type(4))) float f32x4;

__device__ __forceinline__ float4 ld4(const float* p) { return *reinterpret_cast<const float4*>(p); }
__device__ __forceinline__ float2 ld2(const float* p) { return *reinterpret_cast<const float2*>(p); }
__device__ __forceinline__ void st4(float* p, const float4 v) { *reinterpret_cast<float4*>(p) = v; }

__device__ __forceinline__ ushort f2bf(float f) {   // fp32 -> bf16 RNE
    unsigned u = __float_as_uint(f);
    return (ushort)((u + 0x7fffu + ((u >> 16) & 1u)) >> 16);
}
__device__ __forceinline__ float bf2f(ushort h) { return __uint_as_float(((unsigned)h) << 16); }

// async global->LDS, 16B per lane. LDS dest = wave-uniform base + lane*16 (HW);
// global src is per-lane. Size must be a literal.
__device__ __forceinline__ void async16(void* lds, const void* g) {
    __builtin_amdgcn_global_load_lds(
        (const __attribute__((address_space(1))) unsigned int*)g,
        (__attribute__((address_space(3))) unsigned int*)lds,
        16, 0, 0);
}

// LDS activation buffers: [16 rows][128 bf16]. Rows 9-15 hold garbage (scatter
// writes them unguarded; the garbage C-rows they produce are never consumed).
// Row stride 256B => swizzle needed for conflict-free A-frag ds_read_b128 (G4).
#define SWZ(row, c) ((row) * 128 + ((c) ^ (((row) & 7) << 3)))

// ---------------- pre-kernel: fp32 weights -> frag-packed bf16 in d_ws ----------------
// Frag chunk = 64 lanes x 16B (8 bf16, consecutive k). Chunk linear index:
//   gcn : (l*4 + ks)*8 + nt                       (64 chunks,  64 KB)
//   W1  : 64  + ((l*4 + p)*4 + ks)*8 + nt         (256 chunks, 256 KB)
//   W2  : 320 + ((l*4 + p)*4 + ks)*8 + nt         (256 chunks, 256 KB)
// B-frag element j of lane: k = kbase + j, n = nt*16 + (lane&15).
__global__ __launch_bounds__(256)
void pack_weights(const float* __restrict__ gcn_W,
                  const float* __restrict__ ffn_W1,
                  const float* __restrict__ ffn_W2,
                  ushort* __restrict__ wsw)
{
    const int t    = blockIdx.x * 256 + threadIdx.x;  // 0..36863
    const int lane = t & 63;
    const int slot = t >> 6;                          // 0..575
    const int grp  = lane >> 4, cl = lane & 15;

    const float* src; int ldn, kbase, n;
    if (slot < 64) {
        const int l = slot >> 5, ks = (slot >> 3) & 3, nt = slot & 7;
        src = gcn_W + l * RR * RR; ldn = RR;
        kbase = ks * 32 + grp * 8;
        n = nt * 16 + cl;
    } else if (slot < 320) {
        const int s = slot - 64;
        const int l = s >> 7, p = (s >> 5) & 3, ks = (s >> 3) & 3, nt = s & 7;
        src = ffn_W1 + l * RR * FF; ldn = FF;
        kbase = ks * 32 + grp * 8;
        n = p * 128 + nt * 16 + cl;
    } else {
        const int s = slot - 320;
        const int l = s >> 7, p = (s >> 5) & 3, ks = (s >> 3) & 3, nt = s & 7;
        src = ffn_W2 + l * FF * RR; ldn = RR;
        kbase = p * 128 + ks * 32 + grp * 8;
        n = nt * 16 + cl;
    }
    ushort v[8];
    #pragma unroll
    for (int j = 0; j < 8; ++j) v[j] = f2bf(src[(size_t)(kbase + j) * ldn + n]);
    uint4 o;
    o.x = v[0] | ((unsigned)v[1] << 16);
    o.y = v[2] | ((unsigned)v[3] << 16);
    o.z = v[4] | ((unsigned)v[5] << 16);
    o.w = v[6] | ((unsigned)v[7] << 16);
    *reinterpret_cast<uint4*>(wsw + ((size_t)slot * 64 + lane) * 8) = o;
}

// group base (in 1KB-frag units) helpers
__device__ __forceinline__ int gcnB(int l, int ks)        { return (l * 4 + ks) * 8; }
__device__ __forceinline__ int w1B(int l, int p, int ks)  { return 64 + ((l * 4 + p) * 4 + ks) * 8; }
__device__ __forceinline__ int w2B(int l, int p, int ks)  { return 320 + ((l * 4 + p) * 4 + ks) * 8; }

// consume one staged 8-frag group: 8 ds_read_b128 B-frags + 8 MFMA into T[0..7]
#define MMA_GROUP(T, APTR, BUFSEL)                                            \
    {                                                                          \
        const bf16x8 af_ = *(const bf16x8*)(APTR);                             \
        const unsigned char* bb_ = &wbuf[BUFSEL][lane << 4];                   \
        _Pragma("unroll")                                                      \
        for (int nt = 0; nt < 8; ++nt)                                         \
            T[nt] = __builtin_amdgcn_mfma_f32_16x16x32_bf16(                   \
                af_, *(const bf16x8*)(bb_ + (nt << 10)), T[nt], 0, 0, 0);      \
    }

// stage the 8-frag group `fragbase` into wbuf[DST]: each wave stages 2 frags
#define STAGE(DST, FRAGBASE)                                                   \
    {                                                                          \
        const unsigned char* g_ = wsb + ((size_t)((FRAGBASE) + ms * 2) << 10)  \
                                      + (lane << 4);                           \
        async16(&wbuf[DST][(ms * 2) << 10], g_);                               \
        async16(&wbuf[DST][(ms * 2 + 1) << 10], g_ + 1024);                    \
    }

// ---------------- main kernel: one wave per graph, MFMA 16x16x32 bf16,
// block-shared double-buffered LDS weight staging (4 waves share B-frags) ----
__global__ __launch_bounds__(256, 2)
void backbone_mfma(const float* __restrict__ graph,
                   const int*   __restrict__ op_idx,
                   const float* __restrict__ op_table,
                   const float* __restrict__ dev_embed,
                   const float* __restrict__ gcn_b,
                   const float* __restrict__ ln_g,
                   const float* __restrict__ ln_b,
                   const float* __restrict__ ffn_b1,
                   const float* __restrict__ ffn_b2,
                   const float* __restrict__ fc_w,
                   const float* __restrict__ fc_b,
                   const ushort* __restrict__ wsw,
                   float* __restrict__ out)
{
    __shared__ alignas(16) ushort sA[GPB][2048];  // x / h_ln (bf16, swizzled, 16 rows)
    __shared__ alignas(16) ushort sG[GPB][2048];  // agg
    __shared__ alignas(16) ushort sH[GPB][2048];  // ffn hidden chunk
    __shared__ float sNA[GPB][81];
    __shared__ float sD[GPB][NN];
    __shared__ alignas(16) unsigned char wbuf[2][8192];  // weight-group double buffer

    const int tid  = threadIdx.x;
    const int lane = tid & 63;
    const int ms   = tid >> 6;
    const int grp  = lane >> 4;       // k-group for MFMA frags
    const int cl   = lane & 15;       // A-row / C-col
    const int c0   = lane * 2;        // this lane's 2 cols for staging/agg
    const int g    = blockIdx.x * GPB + ms;

    const unsigned char* wsb = (const unsigned char*)wsw;

    // ---- stage x = op_table[op_idx] + dev_embed  (bf16, swizzled rows) ----
    {
        const float2 dv = ld2(&dev_embed[c0]);
        #pragma unroll
        for (int j = 0; j < NN; ++j) {
            const int idx = op_idx[g * NN + j];            // wave-uniform
            float2 v = ld2(&op_table[idx * RR + c0]);
            unsigned pk = f2bf(v.x + dv.x) | ((unsigned)f2bf(v.y + dv.y) << 16);
            *reinterpret_cast<unsigned*>(&sA[ms][SWZ(j, c0)]) = pk;
        }
    }

    // ---- adjacency normalization ----
    {
        const float* gp = graph + (size_t)g * 81;
        {
            const int i = lane / NN, j = lane - i * NN;
            sNA[ms][lane] = gp[lane] + (i == j ? 1.0f : 0.0f);
        }
        if (lane < 17) {
            const int e = lane + 64;
            const int i = e / NN, j = e - i * NN;
            sNA[ms][e] = gp[e] + (i == j ? 1.0f : 0.0f);
        }
        if (lane < NN) {
            float s = 0.f;
            #pragma unroll
            for (int j = 0; j < NN; ++j) s += sNA[ms][lane * NN + j];
            sD[ms][lane] = rsqrtf(s);
        }
        {
            const int i = lane / NN, j = lane - i * NN;
            sNA[ms][lane] *= sD[ms][i] * sD[ms][j];
        }
        if (lane < 17) {
            const int e = lane + 64;
            const int i = e / NN, j = e - i * NN;
            sNA[ms][e] *= sD[ms][i] * sD[ms][j];
        }
    }

    f32x4 acc[8];   // MFMA C-layout accumulator (function scope; readout uses it)

    // prologue: stage first weight group, sync once
    int cur = 0;
    STAGE(0, gcnB(0, 0));
    __syncthreads();

    for (int l = 0; l < LL; ++l) {
        // ---- agg = norm_adj @ x  (fp32 VALU on bf16 x) -> sG bf16 ----
        {
            float xr[NN * 2];
            #pragma unroll
            for (int j = 0; j < NN; ++j) {
                unsigned u = *reinterpret_cast<const unsigned*>(&sA[ms][SWZ(j, c0)]);
                xr[2 * j]     = bf2f((ushort)(u & 0xffffu));
                xr[2 * j + 1] = bf2f((ushort)(u >> 16));
            }
            #pragma unroll
            for (int i = 0; i < NN; ++i) {
                float a0 = 0.f, a1 = 0.f;
                #pragma unroll
                for (int j = 0; j < NN; ++j) {
                    const float w = sNA[ms][i * NN + j];
                    a0 = fmaf(w, xr[2 * j], a0);
                    a1 = fmaf(w, xr[2 * j + 1], a1);
                }
                unsigned pk = f2bf(a0) | ((unsigned)f2bf(a1) << 16);
                *reinterpret_cast<unsigned*>(&sG[ms][SWZ(i, c0)]) = pk;
            }
        }

        // ---- h = agg @ gcn_W via MFMA (4 staged groups) ----
        #pragma unroll
        for (int nt = 0; nt < 8; ++nt) acc[nt] = (f32x4){0.f, 0.f, 0.f, 0.f};
        #pragma unroll
        for (int ks = 0; ks < 4; ++ks) {
            const int nb = (ks < 3) ? gcnB(l, ks + 1) : w1B(l, 0, 0);
            STAGE(cur ^ 1, nb);
            MMA_GROUP(acc, &sG[ms][SWZ(cl, ks * 32 + grp * 8)], cur);
            __syncthreads();
            cur ^= 1;
        }

        // ---- + bias, relu, layernorm (C-layout: col = nt*16+cl, rows grp*4+r) ----
        {
            float sv[4] = {0.f, 0.f, 0.f, 0.f}, qv[4] = {0.f, 0.f, 0.f, 0.f};
            #pragma unroll
            for (int nt = 0; nt < 8; ++nt) {
                const float gb = gcn_b[l * RR + nt * 16 + cl];
                #pragma unroll
                for (int r = 0; r < 4; ++r) {
                    float v = fmaxf(acc[nt][r] + gb, 0.f);
                    acc[nt][r] = v;
                    sv[r] += v; qv[r] += v * v;
                }
            }
            #pragma unroll
            for (int r = 0; r < 4; ++r) {
                #pragma unroll
                for (int m = 1; m <= 8; m <<= 1) {   // row lives in a 16-lane group
                    sv[r] += __shfl_xor(sv[r], m);
                    qv[r] += __shfl_xor(qv[r], m);
                }
            }
            float mu[4], rs[4];
            #pragma unroll
            for (int r = 0; r < 4; ++r) {
                mu[r] = sv[r] * (1.f / RR);
                const float var = qv[r] * (1.f / RR) - mu[r] * mu[r];
                rs[r] = rsqrtf(var + 1e-5f);
            }
            #pragma unroll
            for (int nt = 0; nt < 8; ++nt) {
                const float lgv = ln_g[l * RR + nt * 16 + cl];
                const float lbv = ln_b[l * RR + nt * 16 + cl];
                #pragma unroll
                for (int r = 0; r < 4; ++r)
                    acc[nt][r] = (acc[nt][r] - mu[r]) * rs[r] * lgv + lbv;
            }
        }

        // h_ln -> sA (unguarded scatter; garbage rows 9-15 never consumed)
        #pragma unroll
        for (int nt = 0; nt < 8; ++nt) {
            #pragma unroll
            for (int r = 0; r < 4; ++r)
                sA[ms][SWZ(grp * 4 + r, nt * 16 + cl)] = f2bf(acc[nt][r]);
        }
        // acc becomes the FFN residual accumulator in place: acc += ffn_b2
        #pragma unroll
        for (int nt = 0; nt < 8; ++nt) {
            const float b2v = ffn_b2[l * RR + nt * 16 + cl];
            #pragma unroll
            for (int r = 0; r < 4; ++r) acc[nt][r] += b2v;
        }

        // ---- FFN: 4 passes over F=512 in 128-wide chunks ----
        for (int p = 0; p < 4; ++p) {
            f32x4 t[8];
            #pragma unroll
            for (int nt = 0; nt < 8; ++nt) {
                const float b1v = ffn_b1[l * FF + p * 128 + nt * 16 + cl];
                t[nt] = (f32x4){b1v, b1v, b1v, b1v};
            }
            #pragma unroll
            for (int ks = 0; ks < 4; ++ks) {
                const int nb = (ks < 3) ? w1B(l, p, ks + 1) : w2B(l, p, 0);
                STAGE(cur ^ 1, nb);
                MMA_GROUP(t, &sA[ms][SWZ(cl, ks * 32 + grp * 8)], cur);
                __syncthreads();
                cur ^= 1;
            }
            // relu -> hidden chunk to sH (bf16, unguarded)
            #pragma unroll
            for (int nt = 0; nt < 8; ++nt) {
                #pragma unroll
                for (int r = 0; r < 4; ++r)
                    sH[ms][SWZ(grp * 4 + r, nt * 16 + cl)] = f2bf(fmaxf(t[nt][r], 0.f));
            }
            #pragma unroll
            for (int ks = 0; ks < 4; ++ks) {
                const bool last = (l == LL - 1) && (p == 3) && (ks == 3);
                const int nb = (ks < 3) ? w2B(l, p, ks + 1)
                             : ((p < 3) ? w1B(l, p + 1, 0) : gcnB(l + 1, 0));
                if (!last) STAGE(cur ^ 1, nb);
                MMA_GROUP(acc, &sH[ms][SWZ(cl, ks * 32 + grp * 8)], cur);
                __syncthreads();
                cur ^= 1;
            }
        }

        // next-layer x
        if (l + 1 < LL) {
            #pragma unroll
            for (int nt = 0; nt < 8; ++nt) {
                #pragma unroll
                for (int r = 0; r < 4; ++r)
                    sA[ms][SWZ(grp * 4 + r, nt * 16 + cl)] = f2bf(acc[nt][r]);
            }
        }
    }

    // ---- readout: mean over 9 nodes, dot fc_w, sigmoid ----
    {
        float part = 0.f;
        #pragma unroll
        for (int nt = 0; nt < 8; ++nt) {
            float s = 0.f;
            #pragma unroll
            for (int r = 0; r < 4; ++r) {
                const int row = grp * 4 + r;
                s += (row < NN) ? acc[nt][r] : 0.f;
            }
            s += __shfl_xor(s, 16);
            s += __shfl_xor(s, 32);
            part += s * fc_w[nt * 16 + cl];
        }
        part *= (1.f / 9.f);
        #pragma unroll
        for (int m = 1; m <= 8; m <<= 1) part += __shfl_xor(part, m);
        if (lane == 0) out[g] = 1.f / (1.f + expf(-(part + fc_b[0])));
    }
}

// ---------------- fp32 fallback (round-3 kernel, used if d_ws too small) ----------------
__device__ __forceinline__ void fma4(float4& d, const float a, const float4 w) {
    d.x = fmaf(a, w.x, d.x); d.y = fmaf(a, w.y, d.y);
    d.z = fmaf(a, w.z, d.z); d.w = fmaf(a, w.w, d.w);
}
__device__ __forceinline__ void xadd32(float4& v) {
    v.x += __shfl_xor(v.x, 32); v.y += __shfl_xor(v.y, 32);
    v.z += __shfl_xor(v.z, 32); v.w += __shfl_xor(v.w, 32);
}
__device__ __forceinline__ void relu4f(float4& v) {
    v.x = fmaxf(v.x, 0.f); v.y = fmaxf(v.y, 0.f);
    v.z = fmaxf(v.z, 0.f); v.w = fmaxf(v.w, 0.f);
}

__global__ __launch_bounds__(256)
void backbone_fp32(const float* __restrict__ graph, const int* __restrict__ op_idx,
                   const float* __restrict__ op_table, const float* __restrict__ dev_embed,
                   const float* __restrict__ gcn_W, const float* __restrict__ gcn_b,
                   const float* __restrict__ ln_g, const float* __restrict__ ln_b,
                   const float* __restrict__ ffn_W1, const float* __restrict__ ffn_b1,
                   const float* __restrict__ ffn_W2, const float* __restrict__ ffn_b2,
                   const float* __restrict__ fc_w, const float* __restrict__ fc_b,
                   float* __restrict__ out)
{
    __shared__ float sX[GPB][NN][RR];
    __shared__ float sT[GPB][NN][RR];
    __shared__ float sNA[GPB][81];
    __shared__ float sD[GPB][NN];

    const int tid  = threadIdx.x;
    const int lane = tid & 63;
    const int cg   = tid & 31;
    const int half = (tid >> 5) & 1;
    const int ms   = tid >> 6;
    const int c0   = cg * 4;
    const int k0   = half * 64;
    const int g    = blockIdx.x * GPB + ms;

    {
        const float dv0 = dev_embed[lane];
        const float dv1 = dev_embed[lane + 64];
        #pragma unroll
        for (int j = 0; j < NN; ++j) {
            const int idx = op_idx[g * NN + j];
            sX[ms][j][lane]      = op_table[idx * RR + lane]      + dv0;
            sX[ms][j][lane + 64] = op_table[idx * RR + lane + 64] + dv1;
        }
    }
    {
        const float* gp = graph + (size_t)g * 81;
        { const int i = lane / NN, j = lane - i * NN;
          sNA[ms][lane] = gp[lane] + (i == j ? 1.0f : 0.0f); }
        if (lane < 17) { const int e = lane + 64; const int i = e / NN, j = e - i * NN;
          sNA[ms][e] = gp[e] + (i == j ? 1.0f : 0.0f); }
        if (lane < NN) {
            float s = 0.f;
            #pragma unroll
            for (int j = 0; j < NN; ++j) s += sNA[ms][lane * NN + j];
            sD[ms][lane] = rsqrtf(s);
        }
        { const int i = lane / NN, j = lane - i * NN; sNA[ms][lane] *= sD[ms][i] * sD[ms][j]; }
        if (lane < 17) { const int e = lane + 64; const int i = e / NN, j = e - i * NN;
          sNA[ms][e] *= sD[ms][i] * sD[ms][j]; }
    }

    float4 acc[NN];
    for (int l = 0; l < LL; ++l) {
        const float* gw = gcn_W  + l * RR * RR;
        const float* gb = gcn_b  + l * RR;
        const float* lg = ln_g   + l * RR;
        const float* lb = ln_b   + l * RR;
        const float* w1 = ffn_W1 + l * RR * FF;
        const float* b1 = ffn_b1 + l * FF;
        const float* w2 = ffn_W2 + l * FF * RR;
        const float* b2 = ffn_b2 + l * RR;
        {
            float4 xv[NN];
            #pragma unroll
            for (int j = 0; j < NN; ++j) xv[j] = ld4(&sX[ms][j][c0]);
            #pragma unroll
            for (int ii = 0; ii < 5; ++ii) {
                const int i = ii + half * 5;
                if (i < NN) {
                    float4 a = make_float4(0.f, 0.f, 0.f, 0.f);
                    #pragma unroll
                    for (int j = 0; j < NN; ++j) fma4(a, sNA[ms][i * NN + j], xv[j]);
                    st4(&sT[ms][i][c0], a);
                }
            }
        }
        float4 h[NN];
        {
            const float4 z4 = make_float4(0.f, 0.f, 0.f, 0.f);
            const float4 gbv = ld4(&gb[c0]);
            const float4 ini = half ? z4 : gbv;
            #pragma unroll
            for (int i = 0; i < NN; ++i) h[i] = ini;
            #pragma unroll 2
            for (int kk = 0; kk < 64; kk += 4) {
                const float* wp = gw + (size_t)(k0 + kk) * RR + c0;
                const float4 wv0 = ld4(wp), wv1 = ld4(wp + RR), wv2 = ld4(wp + 2 * RR), wv3 = ld4(wp + 3 * RR);
                #pragma unroll
                for (int i = 0; i < NN; ++i) {
                    const float4 a = ld4(&sT[ms][i][k0 + kk]);
                    fma4(h[i], a.x, wv0); fma4(h[i], a.y, wv1);
                    fma4(h[i], a.z, wv2); fma4(h[i], a.w, wv3);
                }
            }
            #pragma unroll
            for (int i = 0; i < NN; ++i) xadd32(h[i]);
        }
        {
            const float4 lgv = ld4(&lg[c0]);
            const float4 lbv = ld4(&lb[c0]);
            #pragma unroll
            for (int i = 0; i < NN; ++i) {
                float4 v = h[i]; relu4f(v);
                float s = v.x + v.y + v.z + v.w;
                float q = v.x*v.x + v.y*v.y + v.z*v.z + v.w*v.w;
                #pragma unroll
                for (int m = 1; m <= 16; m <<= 1) { s += __shfl_xor(s, m); q += __shfl_xor(q, m); }
                const float mu = s * (1.f / RR);
                const float var = q * (1.f / RR) - mu * mu;
                const float rs = rsqrtf(var + 1e-5f);
                v.x = (v.x - mu) * rs * lgv.x + lbv.x;
                v.y = (v.y - mu) * rs * lgv.y + lbv.y;
                v.z = (v.z - mu) * rs * lgv.z + lbv.z;
                v.w = (v.w - mu) * rs * lgv.w + lbv.w;
                h[i] = v;
            }
        }
        #pragma unroll
        for (int i = 0; i < NN; ++i) st4(&sX[ms][i][c0], h[i]);
        {
            const float4 b2v = ld4(&b2[c0]);
            #pragma unroll
            for (int i = 0; i < NN; ++i) {
                if (half) acc[i] = make_float4(0.f, 0.f, 0.f, 0.f);
                else { acc[i] = h[i];
                       acc[i].x += b2v.x; acc[i].y += b2v.y; acc[i].z += b2v.z; acc[i].w += b2v.w; }
            }
        }
        for (int p = 0; p < 4; ++p) {
            const int f0 = p * RR + c0;
            float4 t[NN];
            {
                const float4 z4 = make_float4(0.f, 0.f, 0.f, 0.f);
                const float4 b1v = ld4(&b1[f0]);
                const float4 ini = half ? z4 : b1v;
                #pragma unroll
                for (int i = 0; i < NN; ++i) t[i] = ini;
            }
            #pragma unroll 2
            for (int kk = 0; kk < 64; kk += 4) {
                const float* wp = w1 + (size_t)(k0 + kk) * FF + f0;
                const float4 wv0 = ld4(wp), wv1 = ld4(wp + FF), wv2 = ld4(wp + 2 * FF), wv3 = ld4(wp + 3 * FF);
                #pragma unroll
                for (int i = 0; i < NN; ++i) {
                    const float4 a = ld4(&sX[ms][i][k0 + kk]);
                    fma4(t[i], a.x, wv0); fma4(t[i], a.y, wv1);
                    fma4(t[i], a.z, wv2); fma4(t[i], a.w, wv3);
                }
            }
            #pragma unroll
            for (int i = 0; i < NN; ++i) { xadd32(t[i]); relu4f(t[i]); st4(&sT[ms][i][c0], t[i]); }
            #pragma unroll 2
            for (int kk = 0; kk < 64; kk += 4) {
                const float* wp = w2 + (size_t)(p * RR + k0 + kk) * RR + c0;
                const float4 wv0 = ld4(wp), wv1 = ld4(wp + RR), wv2 = ld4(wp + 2 * RR), wv3 = ld4(wp + 3 * RR);
                #pragma unroll
                for (int i = 0; i < NN; ++i) {
                    const float4 a = ld4(&sT[ms][i][k0 + kk]);
                    fma4(acc[i], a.x, wv0); fma4(acc[i], a.y, wv1);
                    fma4(acc[i], a.z, wv2); fma4(acc[i], a.w, wv3);
                }
            }
        }
        #pragma unroll
        for (int i = 0; i < NN; ++i) xadd32(acc[i]);
        if (l + 1 < LL) {
            #pragma unroll
            for (int i = 0; i < NN; ++i) st4(&sX[ms][i][c0], acc[i]);
        }
    }
    {
        const float4 fw = ld4(&fc_w[c0]);
        float4 pv = make_float4(0.f, 0.f, 0.f, 0.f);
        #pragma unroll
        for (int i = 0; i < NN; ++i) { pv.x += acc[i].x; pv.y += acc[i].y; pv.z += acc[i].z; pv.w += acc[i].w; }
        float part = (pv.x*fw.x + pv.y*fw.y + pv.z*fw.z + pv.w*fw.w) * (1.f / 9.f);
        #pragma unroll
        for (int m = 1; m <= 16; m <<= 1) part += __shfl_xor(part, m);
        if (lane == 0) out[g] = 1.f / (1.f + expf(-(part + fc_b[0])));
    }
}

extern "C" void kernel_launch(void* const* d_in, const int* in_sizes, int n_in,
                              void* d_out, int out_size, void* d_ws, size_t ws_size,
                              hipStream_t stream) {
    const float* graph     = (const float*)d_in[0];
    const int*   op_idx    = (const int*)  d_in[1];
    const float* op_table  = (const float*)d_in[2];
    const float* dev_embed = (const float*)d_in[3];
    const float* gcn_W     = (const float*)d_in[4];
    const float* gcn_b     = (const float*)d_in[5];
    const float* ln_g      = (const float*)d_in[6];
    const float* ln_b      = (const float*)d_in[7];
    const float* ffn_W1    = (const float*)d_in[8];
    const float* ffn_b1    = (const float*)d_in[9];
    const float* ffn_W2    = (const float*)d_in[10];
    const float* ffn_b2    = (const float*)d_in[11];
    const float* fc_w      = (const float*)d_in[12];
    const float* fc_b      = (const float*)d_in[13];
    float* out = (float*)d_out;

    const int nB = in_sizes[0] / 81;          // 32768
    const size_t WS_NEED = 576 * 1024;        // frag-packed bf16 weights

    if (d_ws != nullptr && ws_size >= WS_NEED) {
        pack_weights<<<dim3(144), dim3(256), 0, stream>>>(gcn_W, ffn_W1, ffn_W2, (ushort*)d_ws);
        backbone_mfma<<<dim3(nB / GPB), dim3(256), 0, stream>>>(
            graph, op_idx, op_table, dev_embed, gcn_b, ln_g, ln_b,
            ffn_b1, ffn_b2, fc_w, fc_b, (const ushort*)d_ws, out);
    } else {
        backbone_fp32<<<dim3(nB / GPB), dim3(256), 0, stream>>>(
            graph, op_idx, op_table, dev_embed, gcn_W, gcn_b, ln_g, ln_b,
            ffn_W1, ffn_b1, ffn_W2, ffn_b2, fc_w, fc_b, out);
    }
}